// Round 6
// baseline (287.026 us; speedup 1.0000x reference)
//
#include <hip/hip_runtime.h>

#define F_EDGE 8
#define H 8
#define EPB 512    // edges per block in the binned edge kernel
#define MAXN 192   // max node span per block for LDS bins (6KB)

__device__ __forceinline__ unsigned short f2bf(float f) {
    unsigned u = __float_as_uint(f);
    unsigned r = u + 0x7fffu + ((u >> 16) & 1u);
    return (unsigned short)(r >> 16);
}
__device__ __forceinline__ float bflo(unsigned u) { return __uint_as_float(u << 16); }
__device__ __forceinline__ float bfhi(unsigned u) { return __uint_as_float(u & 0xffff0000u); }

// ---------------- CSR build: zero, degree, 3-kernel scan, scatter -----------

__global__ __launch_bounds__(256) void zero_kernel(int* __restrict__ p, int n) {
    int i = blockIdx.x * 256 + threadIdx.x;
    if (i < n) p[i] = 0;
}

__global__ __launch_bounds__(256) void degree_kernel(const int* __restrict__ ei,
                                                     int* __restrict__ deg, int E) {
    int e = blockIdx.x * 256 + threadIdx.x;
    if (e < E) atomicAdd(&deg[ei[E + e]], 1);
}

// scanA: each 256-thread block scans 1024 nodes locally (exclusive), emits total.
__global__ __launch_bounds__(256) void scanA_kernel(const int* __restrict__ deg,
                                                    int* __restrict__ off,
                                                    int* __restrict__ bsum, int n) {
    __shared__ int s[256];
    int tid = threadIdx.x;
    int base = blockIdx.x * 1024 + tid * 4;
    int d[4];
    int tsum = 0;
#pragma unroll
    for (int i = 0; i < 4; ++i) {
        d[i] = (base + i < n) ? deg[base + i] : 0;
        tsum += d[i];
    }
    s[tid] = tsum;
    __syncthreads();
    for (int dlt = 1; dlt < 256; dlt <<= 1) {
        int v = (tid >= dlt) ? s[tid - dlt] : 0;
        __syncthreads();
        s[tid] += v;
        __syncthreads();
    }
    int run = s[tid] - tsum;   // exclusive prefix of this thread within block
#pragma unroll
    for (int i = 0; i < 4; ++i) {
        if (base + i < n) off[base + i] = run;
        run += d[i];
    }
    if (tid == 255) bsum[blockIdx.x] = s[255];
}

// scanB: one block turns bsum[nblk] into its exclusive scan, in place. nblk<=256.
__global__ __launch_bounds__(256) void scanB_kernel(int* __restrict__ bsum, int nblk) {
    __shared__ int s[256];
    int tid = threadIdx.x;
    int v = (tid < nblk) ? bsum[tid] : 0;
    s[tid] = v;
    __syncthreads();
    for (int dlt = 1; dlt < 256; dlt <<= 1) {
        int x = (tid >= dlt) ? s[tid - dlt] : 0;
        __syncthreads();
        s[tid] += x;
        __syncthreads();
    }
    if (tid < nblk) bsum[tid] = s[tid] - v;
}

// scanC: add block offsets -> true node-ordered CSR; copy to cursor; sentinel.
__global__ __launch_bounds__(256) void scanC_kernel(int* __restrict__ off,
                                                    int* __restrict__ cur,
                                                    const int* __restrict__ bsum,
                                                    int n, int E) {
    int b = bsum[blockIdx.x];
    int base = blockIdx.x * 1024 + threadIdx.x * 4;
#pragma unroll
    for (int i = 0; i < 4; ++i) {
        int idx = base + i;
        if (idx < n) {
            int v = off[idx] + b;
            off[idx] = v;
            cur[idx] = v;
        }
    }
    if (blockIdx.x == 0 && threadIdx.x == 0) off[n] = E;
}

// Scatter edges into dst-VALUE-ordered position (true CSR). Carries (src,dst)
// + a permuted copy of ea so edge passes read everything streamed.
__global__ __launch_bounds__(256) void scatter_kernel(
    const int* __restrict__ ei, const float* __restrict__ ea,
    int* __restrict__ cur, int2* __restrict__ sd, float* __restrict__ eas,
    int E) {
    int e = blockIdx.x * 256 + threadIdx.x;
    if (e >= E) return;
    int s_ = ei[e];
    int d_ = ei[E + e];
    const float4* av = (const float4*)(ea + (long long)e * F_EDGE);
    float4 a0 = av[0], a1 = av[1];
    int p = atomicAdd(&cur[d_], 1);
    sd[p] = make_int2(s_, d_);
    float4* o = (float4*)(eas + (long long)p * F_EDGE);
    o[0] = a0; o[1] = a1;
}

// ---------------- Per-node precompute (unchanged) ---------------------------
//   Pt[n][j][k]   = sum_i feat[n][i] * We[k][i*H+j]   (stored bf16)
//   q[n][j]       = sum_i feat[n][i] * be[i*H+j]
//   aggseed[n][j] = b[j] + sum_i feat[n][i] * root[i*H+j]
template <int IN, bool RELU, bool INIT>
__global__ __launch_bounds__(256) void prep_kernel(
    const float* __restrict__ feat, const float* __restrict__ We,
    const float* __restrict__ be, const float* __restrict__ root,
    const float* __restrict__ b, unsigned short* __restrict__ Pt,
    float* __restrict__ q, float* __restrict__ aggseed, int n_nodes,
    float* __restrict__ out, const float* __restrict__ blast, int out_n) {
    __shared__ float sW[IN * H * 12];
    int tid = threadIdx.x;
    for (int t = tid; t < IN * H * 12; t += 256) {
        int r = t / 12, m = t - r * 12;   // r = i*H + j
        float v = 0.f;
        if (m < 8) v = We[m * (IN * H) + r];
        else if (m == 8) v = be[r];
        else if (m == 9) v = root[r];
        sW[t] = v;
    }
    if (INIT && blockIdx.x == 0) {
        float bl = blast[0];
        for (int t = tid; t < out_n; t += 256) out[t] = bl;
    }
    __syncthreads();

    int n = blockIdx.x * 32 + (tid >> 3);
    if (n >= n_nodes) return;
    int j = tid & 7;

    float f[IN];
    const float4* fv = (const float4*)(feat + (long long)n * IN);
#pragma unroll
    for (int i4 = 0; i4 < IN / 4; ++i4) {
        float4 v = fv[i4];
        f[i4 * 4 + 0] = v.x; f[i4 * 4 + 1] = v.y;
        f[i4 * 4 + 2] = v.z; f[i4 * 4 + 3] = v.w;
    }
    if (RELU) {
#pragma unroll
        for (int i = 0; i < IN; ++i) f[i] = f[i] > 0.f ? f[i] : 0.f;
    }

    float p[8] = {0.f, 0.f, 0.f, 0.f, 0.f, 0.f, 0.f, 0.f};
    float qq = 0.f, hr = 0.f;
#pragma unroll
    for (int i = 0; i < IN; ++i) {
        const float* row = &sW[(i * 8 + j) * 12];
        float4 w0 = *(const float4*)row;
        float4 w1 = *(const float4*)(row + 4);
        float2 br = *(const float2*)(row + 8);
        float fi = f[i];
        p[0] = fmaf(fi, w0.x, p[0]); p[1] = fmaf(fi, w0.y, p[1]);
        p[2] = fmaf(fi, w0.z, p[2]); p[3] = fmaf(fi, w0.w, p[3]);
        p[4] = fmaf(fi, w1.x, p[4]); p[5] = fmaf(fi, w1.y, p[5]);
        p[6] = fmaf(fi, w1.z, p[6]); p[7] = fmaf(fi, w1.w, p[7]);
        qq = fmaf(fi, br.x, qq);
        hr = fmaf(fi, br.y, hr);
    }
    uint4 pw;
    pw.x = (unsigned)f2bf(p[0]) | ((unsigned)f2bf(p[1]) << 16);
    pw.y = (unsigned)f2bf(p[2]) | ((unsigned)f2bf(p[3]) << 16);
    pw.z = (unsigned)f2bf(p[4]) | ((unsigned)f2bf(p[5]) << 16);
    pw.w = (unsigned)f2bf(p[6]) | ((unsigned)f2bf(p[7]) << 16);
    *(uint4*)(Pt + ((long long)n * H + j) * F_EDGE) = pw;
    q[(long long)n * H + j] = qq;
    aggseed[(long long)n * H + j] = hr + b[j];
}

// ---------------- Binned edge aggregation over true-CSR-ordered edges -------
// dst values are globally non-decreasing in sd[]. A block's EPB consecutive
// edges cover a contiguous node span [lo,hi] (~EPB/meandeg nodes). Flat
// 8-lanes-per-edge main loop (full MLP) accumulates into LDS bins; write-out
// does a plain += for interior nodes (segment fully inside block) and a global
// atomic only for the <=2 boundary nodes per block: 6.4M atomics -> ~25k.
// h must already contain the seed (prep wrote it); zero-degree nodes untouched.
__global__ __launch_bounds__(256) void edge_bin_kernel(
    const int2* __restrict__ sd, const float* __restrict__ eas,
    const unsigned short* __restrict__ Pt, const float* __restrict__ q,
    const int* __restrict__ off, float* __restrict__ h, int E) {
    __shared__ float bins[MAXN * 8];
    int base = blockIdx.x * EPB;
    int cnt = min(EPB, E - base);
    int tid = threadIdx.x;
    int j = tid & 7;

    int lo = sd[base].y;
    int hi = sd[base + cnt - 1].y;
    int span = hi - lo + 1;
    bool binned = (span <= MAXN);

    if (binned) {
        for (int t = tid; t < span * 8; t += 256) bins[t] = 0.f;
        __syncthreads();
    }

#pragma unroll 4
    for (int it = 0; it < EPB / 32; ++it) {
        int k = base + it * 32 + (tid >> 3);
        if (k < base + cnt) {
            int2 se = sd[k];
            const float4* av = (const float4*)(eas + (long long)k * F_EDGE);
            float4 a0 = av[0], a1 = av[1];
            uint4 pw = *(const uint4*)(Pt + ((long long)se.x * H + j) * F_EDGE);
            float m = q[(long long)se.x * H + j];
            m = fmaf(a0.x, bflo(pw.x), m);
            m = fmaf(a0.y, bfhi(pw.x), m);
            m = fmaf(a0.z, bflo(pw.y), m);
            m = fmaf(a0.w, bfhi(pw.y), m);
            m = fmaf(a1.x, bflo(pw.z), m);
            m = fmaf(a1.y, bfhi(pw.z), m);
            m = fmaf(a1.z, bflo(pw.w), m);
            m = fmaf(a1.w, bfhi(pw.w), m);
            if (binned) {
                atomicAdd(&bins[(se.y - lo) * 8 + j], m);   // LDS atomic
            } else {
                unsafeAtomicAdd(&h[(long long)se.y * 8 + j], m);  // rare fallback
            }
        }
    }

    if (binned) {
        __syncthreads();
        int end = base + cnt;
        for (int t = tid; t < span * 8; t += 256) {
            int n = lo + (t >> 3);
            float v = bins[t];
            if (v != 0.f) {
                long long idx = (long long)n * 8 + (t & 7);
                int o0 = off[n], o1 = off[n + 1];
                if (o0 >= base && o1 <= end) {
                    h[idx] += v;                 // interior: exclusive owner
                } else {
                    unsafeAtomicAdd(&h[idx], v); // boundary node
                }
            }
        }
    }
}

// Pool: per-block LDS bins (batch is sorted -> few hot bins per block),
// then one global atomic per nonzero bin.
__global__ __launch_bounds__(256) void pool_kernel(
    const float* __restrict__ h2pre, const int* __restrict__ batch,
    const float* __restrict__ Wlast, float* __restrict__ out,
    int n_nodes, int n_graphs) {
    __shared__ float bins[512];
    bool use_bins = (n_graphs <= 512);
    if (use_bins) {
        for (int t = threadIdx.x; t < n_graphs; t += 256) bins[t] = 0.f;
        __syncthreads();
    }
    float wl[8];
#pragma unroll
    for (int j = 0; j < 8; ++j) wl[j] = Wlast[j];

    int base = blockIdx.x * 1024;
#pragma unroll
    for (int r = 0; r < 4; ++r) {
        int n = base + r * 256 + threadIdx.x;
        if (n < n_nodes) {
            const float4* hv = (const float4*)(h2pre + (long long)n * H);
            float4 h0 = hv[0], h1 = hv[1];
            float c = 0.f;
            c = fmaf(fmaxf(h0.x, 0.f), wl[0], c);
            c = fmaf(fmaxf(h0.y, 0.f), wl[1], c);
            c = fmaf(fmaxf(h0.z, 0.f), wl[2], c);
            c = fmaf(fmaxf(h0.w, 0.f), wl[3], c);
            c = fmaf(fmaxf(h1.x, 0.f), wl[4], c);
            c = fmaf(fmaxf(h1.y, 0.f), wl[5], c);
            c = fmaf(fmaxf(h1.z, 0.f), wl[6], c);
            c = fmaf(fmaxf(h1.w, 0.f), wl[7], c);
            if (use_bins) atomicAdd(&bins[batch[n]], c);
            else unsafeAtomicAdd(&out[batch[n]], c);
        }
    }
    if (use_bins) {
        __syncthreads();
        for (int t = threadIdx.x; t < n_graphs; t += 256) {
            float v = bins[t];
            if (v != 0.f) unsafeAtomicAdd(&out[t], v);
        }
    }
}

extern "C" void kernel_launch(void* const* d_in, const int* in_sizes, int n_in,
                              void* d_out, int out_size, void* d_ws, size_t ws_size,
                              hipStream_t stream) {
    const float* x     = (const float*)d_in[0];
    const int*   ei    = (const int*)d_in[1];
    const float* ea    = (const float*)d_in[2];
    const int*   batch = (const int*)d_in[3];
    const float* We1   = (const float*)d_in[4];
    const float* be1   = (const float*)d_in[5];
    const float* root1 = (const float*)d_in[6];
    const float* b1    = (const float*)d_in[7];
    const float* We2   = (const float*)d_in[8];
    const float* be2   = (const float*)d_in[9];
    const float* root2 = (const float*)d_in[10];
    const float* b2    = (const float*)d_in[11];
    const float* Wlast = (const float*)d_in[12];
    const float* blast = (const float*)d_in[13];
    float* out = (float*)d_out;

    int F_IN_rt = 16;
    int n_nodes = in_sizes[0] / F_IN_rt;
    int E = in_sizes[1] / 2;

    char* w = (char*)d_ws;
    auto take = [&](size_t bytes) {
        char* p = w;
        w += (bytes + 15) & ~(size_t)15;
        return p;
    };
    unsigned short* Pt1 = (unsigned short*)take((size_t)n_nodes * H * F_EDGE * 2);
    unsigned short* Pt2 = (unsigned short*)take((size_t)n_nodes * H * F_EDGE * 2);
    float* q1    = (float*)take((size_t)n_nodes * H * 4);
    float* q2    = (float*)take((size_t)n_nodes * H * 4);
    float* h1    = (float*)take((size_t)n_nodes * H * 4);   // seed1 -> h1 in place
    float* h2    = (float*)take((size_t)n_nodes * H * 4);   // seed2 -> h2 in place
    int* deg     = (int*)take((size_t)n_nodes * 4);
    int* off     = (int*)take((size_t)(n_nodes + 1) * 4);
    int* cur     = (int*)take((size_t)n_nodes * 4);
    int* bsum    = (int*)take((size_t)256 * 4);
    int2* sd     = (int2*)take((size_t)E * 8);
    float* eas   = (float*)take((size_t)E * F_EDGE * 4);

    int nbn = (n_nodes + 255) / 256;
    int nbe = (E + 255) / 256;
    int nscan = (n_nodes + 1023) / 1024;   // <= 256 required (n_nodes <= 256K)

    // true node-ordered CSR build
    zero_kernel<<<nbn, 256, 0, stream>>>(deg, n_nodes);
    degree_kernel<<<nbe, 256, 0, stream>>>(ei, deg, E);
    scanA_kernel<<<nscan, 256, 0, stream>>>(deg, off, bsum, n_nodes);
    scanB_kernel<<<1, 256, 0, stream>>>(bsum, nscan);
    scanC_kernel<<<nscan, 256, 0, stream>>>(off, cur, bsum, n_nodes, E);
    scatter_kernel<<<nbe, 256, 0, stream>>>(ei, ea, cur, sd, eas, E);

    int nblocks = (n_nodes + 31) / 32;
    prep_kernel<16, false, true><<<nblocks, 256, 0, stream>>>(
        x, We1, be1, root1, b1, Pt1, q1, h1, n_nodes, out, blast, out_size);

    int eblks = (E + EPB - 1) / EPB;
    edge_bin_kernel<<<eblks, 256, 0, stream>>>(sd, eas, Pt1, q1, off, h1, E);

    prep_kernel<H, true, false><<<nblocks, 256, 0, stream>>>(
        h1, We2, be2, root2, b2, Pt2, q2, h2, n_nodes, nullptr, nullptr, 0);

    edge_bin_kernel<<<eblks, 256, 0, stream>>>(sd, eas, Pt2, q2, off, h2, E);

    int pblocks = (n_nodes + 1023) / 1024;
    pool_kernel<<<pblocks, 256, 0, stream>>>(h2, batch, Wlast, out, n_nodes, out_size);
}

// Round 7
// 204.271 us; speedup vs baseline: 1.4051x; 1.4051x over previous
//
#include <hip/hip_runtime.h>

#define F_EDGE 8
#define H 8

__device__ __forceinline__ unsigned short f2bf(float f) {
    unsigned u = __float_as_uint(f);
    unsigned r = u + 0x7fffu + ((u >> 16) & 1u);
    return (unsigned short)(r >> 16);
}
__device__ __forceinline__ float bflo(unsigned u) { return __uint_as_float(u << 16); }
__device__ __forceinline__ float bfhi(unsigned u) { return __uint_as_float(u & 0xffff0000u); }

// ---------------- Edge-stream pack: (src,dst) int2 + ea -> bf16x8 -----------
// Fully streamed both ways (~32MB read, ~19MB write). Halves the per-pass ea
// bytes (25.6 -> 12.8 MB) and gives each edge pass an 8B index record.
__global__ __launch_bounds__(256) void pack_kernel(
    const int* __restrict__ ei, const float* __restrict__ ea,
    int2* __restrict__ sd, unsigned short* __restrict__ eab, int E) {
    int e = blockIdx.x * 256 + threadIdx.x;
    if (e >= E) return;
    sd[e] = make_int2(ei[e], ei[E + e]);
    const float4* av = (const float4*)(ea + (long long)e * F_EDGE);
    float4 a0 = av[0], a1 = av[1];
    uint4 pw;
    pw.x = (unsigned)f2bf(a0.x) | ((unsigned)f2bf(a0.y) << 16);
    pw.y = (unsigned)f2bf(a0.z) | ((unsigned)f2bf(a0.w) << 16);
    pw.z = (unsigned)f2bf(a1.x) | ((unsigned)f2bf(a1.y) << 16);
    pw.w = (unsigned)f2bf(a1.z) | ((unsigned)f2bf(a1.w) << 16);
    *(uint4*)(eab + (long long)e * F_EDGE) = pw;
}

// ---------------- Per-node precompute (proven) ------------------------------
//   Pt[n][j][k]   = sum_i feat[n][i] * We[k][i*H+j]   (stored bf16)
//   q[n][j]       = sum_i feat[n][i] * be[i*H+j]
//   aggseed[n][j] = b[j] + sum_i feat[n][i] * root[i*H+j]
// INIT=true: block 0 additionally seeds out[g] = blast[0].
template <int IN, bool RELU, bool INIT>
__global__ __launch_bounds__(256) void prep_kernel(
    const float* __restrict__ feat, const float* __restrict__ We,
    const float* __restrict__ be, const float* __restrict__ root,
    const float* __restrict__ b, unsigned short* __restrict__ Pt,
    float* __restrict__ q, float* __restrict__ aggseed, int n_nodes,
    float* __restrict__ out, const float* __restrict__ blast, int out_n) {
    __shared__ float sW[IN * H * 12];
    int tid = threadIdx.x;
    for (int t = tid; t < IN * H * 12; t += 256) {
        int r = t / 12, m = t - r * 12;   // r = i*H + j
        float v = 0.f;
        if (m < 8) v = We[m * (IN * H) + r];
        else if (m == 8) v = be[r];
        else if (m == 9) v = root[r];
        sW[t] = v;
    }
    if (INIT && blockIdx.x == 0) {
        float bl = blast[0];
        for (int t = tid; t < out_n; t += 256) out[t] = bl;
    }
    __syncthreads();

    int n = blockIdx.x * 32 + (tid >> 3);
    if (n >= n_nodes) return;
    int j = tid & 7;

    float f[IN];
    const float4* fv = (const float4*)(feat + (long long)n * IN);
#pragma unroll
    for (int i4 = 0; i4 < IN / 4; ++i4) {
        float4 v = fv[i4];
        f[i4 * 4 + 0] = v.x; f[i4 * 4 + 1] = v.y;
        f[i4 * 4 + 2] = v.z; f[i4 * 4 + 3] = v.w;
    }
    if (RELU) {
#pragma unroll
        for (int i = 0; i < IN; ++i) f[i] = f[i] > 0.f ? f[i] : 0.f;
    }

    float p[8] = {0.f, 0.f, 0.f, 0.f, 0.f, 0.f, 0.f, 0.f};
    float qq = 0.f, hr = 0.f;
#pragma unroll
    for (int i = 0; i < IN; ++i) {
        const float* row = &sW[(i * 8 + j) * 12];
        float4 w0 = *(const float4*)row;
        float4 w1 = *(const float4*)(row + 4);
        float2 br = *(const float2*)(row + 8);
        float fi = f[i];
        p[0] = fmaf(fi, w0.x, p[0]); p[1] = fmaf(fi, w0.y, p[1]);
        p[2] = fmaf(fi, w0.z, p[2]); p[3] = fmaf(fi, w0.w, p[3]);
        p[4] = fmaf(fi, w1.x, p[4]); p[5] = fmaf(fi, w1.y, p[5]);
        p[6] = fmaf(fi, w1.z, p[6]); p[7] = fmaf(fi, w1.w, p[7]);
        qq = fmaf(fi, br.x, qq);
        hr = fmaf(fi, br.y, hr);
    }
    uint4 pw;
    pw.x = (unsigned)f2bf(p[0]) | ((unsigned)f2bf(p[1]) << 16);
    pw.y = (unsigned)f2bf(p[2]) | ((unsigned)f2bf(p[3]) << 16);
    pw.z = (unsigned)f2bf(p[4]) | ((unsigned)f2bf(p[5]) << 16);
    pw.w = (unsigned)f2bf(p[6]) | ((unsigned)f2bf(p[7]) << 16);
    *(uint4*)(Pt + ((long long)n * H + j) * F_EDGE) = pw;
    q[(long long)n * H + j] = qq;
    aggseed[(long long)n * H + j] = hr + b[j];
}

// ---------------- Flat edge kernel (R0 structure, thinned stream) -----------
// 8 lanes per edge; per edge: sd 8B (broadcast), eab 16B (broadcast),
// Pt row 16B/lane (one 128B line/edge), q 4B/lane (32B line/edge).
//   msg_j = q[src][j] + sum_k eab[e][k] * Pt[src][j][k]
//   atomicAdd(agg[dst][j], msg_j)
__global__ __launch_bounds__(256) void edge_fact_kernel(
    const int2* __restrict__ sd, const unsigned short* __restrict__ eab,
    const unsigned short* __restrict__ Pt, const float* __restrict__ q,
    float* __restrict__ agg, int E) {
    long long gid = (long long)blockIdx.x * 256 + threadIdx.x;
    int e = (int)(gid >> 3);
    if (e >= E) return;
    int j = (int)(gid & 7);

    int2 se = sd[e];
    uint4 av = *(const uint4*)(eab + (long long)e * F_EDGE);
    uint4 pw = *(const uint4*)(Pt + ((long long)se.x * H + j) * F_EDGE);
    float m = q[(long long)se.x * H + j];

    m = fmaf(bflo(av.x), bflo(pw.x), m);
    m = fmaf(bfhi(av.x), bfhi(pw.x), m);
    m = fmaf(bflo(av.y), bflo(pw.y), m);
    m = fmaf(bfhi(av.y), bfhi(pw.y), m);
    m = fmaf(bflo(av.z), bflo(pw.z), m);
    m = fmaf(bfhi(av.z), bfhi(pw.z), m);
    m = fmaf(bflo(av.w), bflo(pw.w), m);
    m = fmaf(bfhi(av.w), bfhi(pw.w), m);

    unsafeAtomicAdd(&agg[(long long)se.y * H + j], m);
}

// Pool: per-block LDS bins (batch is sorted -> few hot bins per block),
// then one global atomic per nonzero bin.
__global__ __launch_bounds__(256) void pool_kernel(
    const float* __restrict__ h2pre, const int* __restrict__ batch,
    const float* __restrict__ Wlast, float* __restrict__ out,
    int n_nodes, int n_graphs) {
    __shared__ float bins[512];
    bool use_bins = (n_graphs <= 512);
    if (use_bins) {
        for (int t = threadIdx.x; t < n_graphs; t += 256) bins[t] = 0.f;
        __syncthreads();
    }
    float wl[8];
#pragma unroll
    for (int j = 0; j < 8; ++j) wl[j] = Wlast[j];

    int base = blockIdx.x * 1024;
#pragma unroll
    for (int r = 0; r < 4; ++r) {
        int n = base + r * 256 + threadIdx.x;
        if (n < n_nodes) {
            const float4* hv = (const float4*)(h2pre + (long long)n * H);
            float4 h0 = hv[0], h1 = hv[1];
            float c = 0.f;
            c = fmaf(fmaxf(h0.x, 0.f), wl[0], c);
            c = fmaf(fmaxf(h0.y, 0.f), wl[1], c);
            c = fmaf(fmaxf(h0.z, 0.f), wl[2], c);
            c = fmaf(fmaxf(h0.w, 0.f), wl[3], c);
            c = fmaf(fmaxf(h1.x, 0.f), wl[4], c);
            c = fmaf(fmaxf(h1.y, 0.f), wl[5], c);
            c = fmaf(fmaxf(h1.z, 0.f), wl[6], c);
            c = fmaf(fmaxf(h1.w, 0.f), wl[7], c);
            if (use_bins) atomicAdd(&bins[batch[n]], c);
            else unsafeAtomicAdd(&out[batch[n]], c);
        }
    }
    if (use_bins) {
        __syncthreads();
        for (int t = threadIdx.x; t < n_graphs; t += 256) {
            float v = bins[t];
            if (v != 0.f) unsafeAtomicAdd(&out[t], v);
        }
    }
}

extern "C" void kernel_launch(void* const* d_in, const int* in_sizes, int n_in,
                              void* d_out, int out_size, void* d_ws, size_t ws_size,
                              hipStream_t stream) {
    const float* x     = (const float*)d_in[0];
    const int*   ei    = (const int*)d_in[1];
    const float* ea    = (const float*)d_in[2];
    const int*   batch = (const int*)d_in[3];
    const float* We1   = (const float*)d_in[4];
    const float* be1   = (const float*)d_in[5];
    const float* root1 = (const float*)d_in[6];
    const float* b1    = (const float*)d_in[7];
    const float* We2   = (const float*)d_in[8];
    const float* be2   = (const float*)d_in[9];
    const float* root2 = (const float*)d_in[10];
    const float* b2    = (const float*)d_in[11];
    const float* Wlast = (const float*)d_in[12];
    const float* blast = (const float*)d_in[13];
    float* out = (float*)d_out;

    int F_IN_rt = 16;
    int n_nodes = in_sizes[0] / F_IN_rt;
    int E = in_sizes[1] / 2;

    char* w = (char*)d_ws;
    auto take = [&](size_t bytes) {
        char* p = w;
        w += (bytes + 15) & ~(size_t)15;
        return p;
    };
    unsigned short* Pt1 = (unsigned short*)take((size_t)n_nodes * H * F_EDGE * 2);
    unsigned short* Pt2 = (unsigned short*)take((size_t)n_nodes * H * F_EDGE * 2);
    float* q1    = (float*)take((size_t)n_nodes * H * 4);
    float* q2    = (float*)take((size_t)n_nodes * H * 4);
    float* h1    = (float*)take((size_t)n_nodes * H * 4);   // seed1 -> h1 in place
    float* h2    = (float*)take((size_t)n_nodes * H * 4);   // seed2 -> h2 in place
    int2* sd     = (int2*)take((size_t)E * 8);
    unsigned short* eab = (unsigned short*)take((size_t)E * F_EDGE * 2);

    int nbe = (E + 255) / 256;

    // streamed edge pack: ea fp32 -> bf16, ei -> int2 records
    pack_kernel<<<nbe, 256, 0, stream>>>(ei, ea, sd, eab, E);

    int nblocks = (n_nodes + 31) / 32;
    // prep1 also seeds out[g] = blast[0] (block 0)
    prep_kernel<16, false, true><<<nblocks, 256, 0, stream>>>(
        x, We1, be1, root1, b1, Pt1, q1, h1, n_nodes, out, blast, out_size);

    long long lanes = (long long)E * H;
    int eblks = (int)((lanes + 255) / 256);
    edge_fact_kernel<<<eblks, 256, 0, stream>>>(sd, eab, Pt1, q1, h1, E);

    prep_kernel<H, true, false><<<nblocks, 256, 0, stream>>>(
        h1, We2, be2, root2, b2, Pt2, q2, h2, n_nodes, nullptr, nullptr, 0);

    edge_fact_kernel<<<eblks, 256, 0, stream>>>(sd, eab, Pt2, q2, h2, E);

    int pblocks = (n_nodes + 1023) / 1024;
    pool_kernel<<<pblocks, 256, 0, stream>>>(h2, batch, Wlast, out, n_nodes, out_size);
}